// Round 10
// baseline (278.986 us; speedup 1.0000x reference)
//
#include <hip/hip_runtime.h>
#include <math.h>

// CrossViewSwapAttention forward. Round 10: LN folded into projection weights
// (conv emits pre-normalized K1n/V1n, tail1 emits Q1n; prep scales W by g and
// folds lnb@W into biases) -> all projections are pure bf16 GEMMs with
// MT=128 tiles. 8 dispatches.
// B=2 N=6 H=W=64 FH=32 FW=88 DIM=128 HEADS=4 DH=32 QW=8x8 KW=4x11

typedef __attribute__((ext_vector_type(8))) short short8;
typedef __attribute__((ext_vector_type(4))) float f32x4;

__device__ __forceinline__ unsigned short f2bf(float f){
  union { float f; unsigned u; } v; v.f = f;
  unsigned r = v.u + 0x7FFF + ((v.u >> 16) & 1);   // RNE
  return (unsigned short)(r >> 16);
}
__device__ __forceinline__ float bf2f(unsigned short h){
  union { unsigned u; float f; } v; v.u = ((unsigned)h) << 16; return v.f;
}
__device__ __forceinline__ void store_bf16x8(unsigned short* p, const float* v){
  union { short8 s8; unsigned short u[8]; } u;
  #pragma unroll
  for (int i=0;i<8;i++) u.u[i] = f2bf(v[i]);
  *(short8*)p = u.s8;
}

__device__ __forceinline__ float gelu_erf(float x){
  float z = x * 0.70710678118654752f;
  float a = fabsf(z);
  float t = 1.0f / fmaf(0.3275911f, a, 1.0f);
  float p = t*(0.254829592f + t*(-0.284496736f + t*(1.421413741f +
            t*(-1.453152027f + t*1.061405429f))));
  float er = 1.0f - p*__expf(-a*a);
  er = copysignf(er, z);
  return 0.5f * x * (1.0f + er);
}

__device__ __forceinline__ size_t remap_kv(int tok, int mode){
  int bn = tok / 2816; int p = tok - bn*2816;
  int b = bn / 6, n = bn - b*6;
  int i = p / 88, j = p - i*88;
  int l, t;
  if (mode == 1){
    int jw = j / 11;
    l = (i >> 2)*8 + jw;
    t = n*44 + (i & 3)*11 + (j - jw*11);
  } else {
    l = (i & 7)*8 + (j & 7);
    t = n*44 + (i >> 3)*11 + (j >> 3);
  }
  return (size_t)((b*64 + l)*264 + t);
}

// ---------------- fused prep: wprep(+g-fold) | bias-fold | geom | bevq ------
__global__ __launch_bounds__(128) void k_prep(
    const float* __restrict__ qkv, const float* __restrict__ wp,
    const float* __restrict__ wma, const float* __restrict__ wmb,
    const float* __restrict__ wfl, const float* __restrict__ wfp,
    unsigned short* __restrict__ Wt,
    const float* __restrict__ Iinv, const float* __restrict__ Einv,
    const float* __restrict__ Wimg, const float* __restrict__ Wcam,
    unsigned short* __restrict__ K1h,
    const float* __restrict__ gridp, const float* __restrict__ Wbev,
    const float* __restrict__ bbev, const float* __restrict__ x,
    const float* __restrict__ lg, const float* __restrict__ lb,
    const float* __restrict__ abqkv, float* __restrict__ biasP,
    unsigned short* __restrict__ Qh){
  __shared__ float sx[128][9];
  int bid = blockIdx.x;
  if (bid < 64){
    const int sel[16]  = {0,0,0,0,0,0, 1,1, 2,2, 3,3,3,3, 4,5};
    const int soff[16] = {0,16384,32768,49152,65536,81920, 0,16384, 0,32768,
                          0,16384,32768,49152, 0,0};
    const int doff[16] = {0,16384,32768,49152,65536,81920, 98304,114688,
                          131072,163840, 196608,212992,229376,245760, 262144,278528};
    const int Ns[16]   = {128,128,128,128,128,128, 128,128, 256,256,
                          128,128,128,128, 128,128};
    const int trs[16]  = {1,1,1,1,1,1, 1,1, 1,1, 1,1,1,1, 0,0};
    int sg = bid >> 2, q = bid & 3;
    const float* srcs[6] = {qkv, wp, wma, wmb, wfl, wfp};
    const float* src = srcs[sel[sg]] + soff[sg];
    unsigned short* dst = Wt + doff[sg];
    int K = 128, N = Ns[sg];
    int quarter = (K*N) >> 2;
    bool fold = (sg >= 1 && sg <= 5);       // K1,V1,Q2,K2,V2 qkv weights
    const float* gv = lg + sg*128;          // alng[sg*128 + k]
    for (int idx = q*quarter + threadIdx.x; idx < (q+1)*quarter; idx += 128){
      int n = idx / K, k = idx - n*K;
      float v = trs[sg] ? src[k*N + n] : src[idx];
      if (fold) v *= gv[k];
      dst[idx] = f2bf(v);
    }
  } else if (bid < 70){
    // folded biases for the 6 qkv projections
    int m = bid - 64;
    int n = threadIdx.x;
    float s = abqkv[m*128 + n];
    if (m > 0){
      const float* lnb = lb + m*128;
      const float* W = qkv + m*16384;
      for (int k=0;k<128;k++) s = fmaf(lnb[k], W[k*128 + n], s);
    }
    biasP[m*128 + n] = s;
  } else if (bid < 4294){
    int tile = bid - 70;
    int bn = tile / 352; int p0 = (tile - bn*352)*8;
    int xid = threadIdx.x >> 4, part = threadIdx.x & 15;
    int p = p0 + xid;
    int i = p / 88, j = p - i*88;
    float xs = (float)j * (480.0f/87.0f);
    float ys = (float)i * (224.0f/31.0f);
    const float* I = Iinv + bn*9;
    const float* E = Einv + bn*16;
    float c0 = I[0]*xs + I[1]*ys + I[2];
    float c1 = I[3]*xs + I[4]*ys + I[5];
    float c2 = I[6]*xs + I[7]*ys + I[8];
    float d0 = E[0]*c0 + E[1]*c1 + E[2]*c2 + E[3];
    float d1 = E[4]*c0 + E[5]*c1 + E[6]*c2 + E[7];
    float d2 = E[8]*c0 + E[9]*c1 + E[10]*c2 + E[11];
    float d3 = E[12]*c0 + E[13]*c1 + E[14]*c2 + E[15];
    float v[8]; float sq = 0.f;
    #pragma unroll
    for (int k=0;k<8;k++){
      int o = part*8 + k;
      const float* W = Wimg + o*4;
      const float* Wc = Wcam + o*4;
      float de = W[0]*d0 + W[1]*d1 + W[2]*d2 + W[3]*d3;
      float ce = Wc[0]*E[3] + Wc[1]*E[7] + Wc[2]*E[11] + Wc[3]*E[15];
      float vv = de - ce;
      v[k] = vv; sq = fmaf(vv, vv, sq);
    }
    #pragma unroll
    for (int off=8; off>0; off>>=1) sq += __shfl_xor(sq, off, 16);
    float rn = 1.0f / fmaxf(sqrtf(sq), 1e-12f);
    float o8[8];
    #pragma unroll
    for (int k=0;k<8;k++) o8[k] = v[k]*rn;
    store_bf16x8(K1h + (size_t)(bn*2816 + p)*128 + part*8, o8);
  } else {
    int bid2 = bid - 4294;
    int b = bid2 >> 9; int pp0 = (bid2 & 511) << 3;
    {
      int cg = threadIdx.x >> 3, px = threadIdx.x & 7;
      #pragma unroll
      for (int i=0;i<8;i++){
        int c = cg + 16*i;
        sx[c][px] = x[(size_t)b*524288 + (size_t)c*4096 + pp0 + px];
      }
    }
    __syncthreads();
    int xid = threadIdx.x >> 4, part = threadIdx.x & 15;
    int pix = pp0 + xid;
    int h = pix >> 6, w = pix & 63;
    int l = (h>>3)*8 + (w>>3);
    int tq = (h&7)*8 + (w&7);
    float g0 = gridp[pix], g1 = gridp[4096 + pix];
    float we[8], xv[8];
    #pragma unroll
    for (int k=0;k<8;k++){
      int o = part*8 + k;
      we[k] = Wbev[o*2]*g0 + Wbev[o*2+1]*g1 + bbev[o];
      xv[k] = sx[part*8+k][xid];
    }
    for (int n=0; n<6; n++){
      const float* E = Einv + (b*6+n)*16;
      float v[8]; float sq = 0.f;
      #pragma unroll
      for (int k=0;k<8;k++){
        int o = part*8 + k;
        const float* Wc = Wcam + o*4;
        float ce = Wc[0]*E[3] + Wc[1]*E[7] + Wc[2]*E[11] + Wc[3]*E[15];
        float vv = we[k] - ce;
        v[k] = vv; sq = fmaf(vv, vv, sq);
      }
      #pragma unroll
      for (int off=8; off>0; off>>=1) sq += __shfl_xor(sq, off, 16);
      float rn = 1.0f / fmaxf(sqrtf(sq), 1e-12f);
      float q[8]; float s=0.f, s2=0.f;
      #pragma unroll
      for (int k=0;k<8;k++){
        q[k] = fmaf(v[k], rn, xv[k]);
        s += q[k]; s2 = fmaf(q[k], q[k], s2);
      }
      #pragma unroll
      for (int off=8; off>0; off>>=1){ s += __shfl_xor(s, off, 16); s2 += __shfl_xor(s2, off, 16); }
      float mean = s*(1.f/128.f);
      float rstd = rsqrtf(fmaxf(s2*(1.f/128.f) - mean*mean, 0.f) + 1e-5f);
      size_t row = (size_t)((b*64 + l)*384 + n*64 + tq);
      float o8[8];
      #pragma unroll
      for (int k=0;k<8;k++){
        int c = part*8 + k;
        o8[k] = fmaf((q[k]-mean)*rstd, lg[c], lb[c]);
      }
      store_bf16x8(Qh + row*128 + part*8, o8);
    }
  }
}

// ---------------- conv + row-normalize (emits K1n/V1n), MT=128 --------------
__global__ __launch_bounds__(256) void k_conv(const float* __restrict__ feat,
    const float* __restrict__ gK, const float* __restrict__ bK,
    const unsigned short* __restrict__ WK, unsigned short* __restrict__ K1h,
    const float* __restrict__ gV, const float* __restrict__ bV,
    const unsigned short* __restrict__ WV, unsigned short* __restrict__ V1h){
  constexpr int KP_ = 136;
  __shared__ unsigned short sW[128*KP_];
  __shared__ unsigned short sA[128*KP_];
  __shared__ float sg[128], sb[128];
  __shared__ float sMean[128], sRstd[128];
  const int which = (blockIdx.x >= 264);
  const int bid = which ? blockIdx.x - 264 : blockIdx.x;
  const float* gg = which ? gV : gK;
  const float* bb = which ? bV : bK;
  const unsigned short* Wts = which ? WV : WK;
  unsigned short* OUT = which ? V1h : K1h;
  const int tid = threadIdx.x;
  const int base = bid * 128;
  for (int i = tid; i < 2048; i += 256){
    int n = i >> 4, k8 = (i & 15) << 3;
    *(short8*)&sW[n*KP_ + k8] = *(const short8*)(Wts + (size_t)n*128 + k8);
  }
  if (tid < 128){ sg[tid]=gg[tid]; sb[tid]=bb[tid]; }
  const float RSQ = rsqrtf(1.0f + 1e-5f);
  {
    int prow = tid & 127, cseg = tid >> 7;     // 2 segments x 64 channels
    int bn = base / 2816;                      // 2816 % 128 == 0
    int p = base - bn*2816 + prow;
    const float* fb = feat + ((size_t)bn*128 + cseg*64)*2816 + p;
    #pragma unroll 8
    for (int i=0;i<64;i+=2){
      int c = cseg*64 + i;
      float t0 = fb[(size_t)i*2816] * RSQ;
      float t1 = fb[(size_t)(i+1)*2816] * RSQ;
      float y0 = fmaxf(fmaf(t0, sg[c],   sb[c]),   0.f);
      float y1 = fmaxf(fmaf(t1, sg[c+1], sb[c+1]), 0.f);
      unsigned u = (unsigned)f2bf(y0) | ((unsigned)f2bf(y1) << 16);
      *(unsigned*)&sA[prow*KP_ + c] = u;
    }
  }
  __syncthreads();
  const int lane = tid & 63, wv = tid >> 6;
  const int lane15 = lane & 15, quad = lane >> 4;
  const int n0 = wv * 32;
  f32x4 acc[8][2];
  #pragma unroll
  for (int mt=0; mt<8; mt++){ acc[mt][0]=(f32x4)0.f; acc[mt][1]=(f32x4)0.f; }
  const unsigned short* aptr = sA + lane15*KP_ + quad*8;
  const unsigned short* bptr = sW + (size_t)(n0 + lane15)*KP_ + quad*8;
  #pragma unroll
  for (int kk=0; kk<4; kk++){
    short8 af[8], bf2v[2];
    #pragma unroll
    for (int mt=0; mt<8; mt++) af[mt] = *(const short8*)(aptr + mt*16*KP_ + kk*32);
    bf2v[0] = *(const short8*)(bptr + kk*32);
    bf2v[1] = *(const short8*)(bptr + 16*KP_ + kk*32);
    #pragma unroll
    for (int mt=0; mt<8; mt++){
      acc[mt][0] = __builtin_amdgcn_mfma_f32_16x16x32_bf16(af[mt], bf2v[0], acc[mt][0], 0,0,0);
      acc[mt][1] = __builtin_amdgcn_mfma_f32_16x16x32_bf16(af[mt], bf2v[1], acc[mt][1], 0,0,0);
    }
  }
  __syncthreads();
  #pragma unroll
  for (int mt=0; mt<8; mt++){
    #pragma unroll
    for (int nt=0; nt<2; nt++){
      int col = n0 + nt*16 + lane15;
      #pragma unroll
      for (int r4=0; r4<4; r4++){
        int row = mt*16 + quad*4 + r4;
        float v = acc[mt][nt][r4];
        if (!which) v += bf2f(K1h[(size_t)(base+row)*128 + col]);   // + geom
        sA[row*KP_ + col] = f2bf(v);
      }
    }
  }
  __syncthreads();
  // row LN stats (affine-free; affine folded into projection weights)
  {
    int r = tid >> 1, part = tid & 1;
    float s=0.f, s2=0.f;
    #pragma unroll 8
    for (int k=0;k<64;k++){
      float v = bf2f(sA[r*KP_ + part*64 + k]);
      s += v; s2 = fmaf(v,v,s2);
    }
    s += __shfl_xor(s, 1); s2 += __shfl_xor(s2, 1);
    if (part == 0){
      float mean = s*(1.f/128.f);
      sMean[r] = mean;
      sRstd[r] = rsqrtf(fmaxf(s2*(1.f/128.f) - mean*mean, 0.f) + 1e-5f);
    }
  }
  __syncthreads();
  for (int i = tid; i < 2048; i += 256){
    int row = i >> 4, seg = i & 15;
    float mean = sMean[row], rstd = sRstd[row];
    union { short8 s; unsigned short u[8]; } t;
    t.s = *(const short8*)&sA[row*KP_ + seg*8];
    float v[8];
    #pragma unroll
    for (int k=0;k<8;k++) v[k] = (bf2f(t.u[k]) - mean)*rstd;
    store_bf16x8(OUT + (size_t)(base+row)*128 + seg*8, v);
  }
}

// ---------------- pure bf16 3-role GEMM, MT=128 -----------------------------
struct GArg {
  const unsigned short* Xh;
  const unsigned short* Wt; const float* bias;
  unsigned short* OUTH; float oscale; int outmode;
};

__global__ __launch_bounds__(256) void k_qkv(GArg ga, GArg gb, GArg gc,
                                             int s1, int s2){
  constexpr int KP_ = 136;
  __shared__ unsigned short sW[128*KP_];
  __shared__ unsigned short sA[128*KP_];
  __shared__ float sbias[128];
  const int b0 = (int)blockIdx.x;
  const GArg g = (b0 < s1) ? ga : (b0 < s2) ? gb : gc;
  const int bid = (b0 < s1) ? b0 : (b0 < s2) ? b0 - s1 : b0 - s2;
  const int base = bid * 128;
  const int tid = threadIdx.x;
  for (int i = tid; i < 2048; i += 256){
    int n = i >> 4, k8 = (i & 15) << 3;
    *(short8*)&sW[n*KP_ + k8] = *(const short8*)(g.Wt + (size_t)n*128 + k8);
  }
  if (tid < 128) sbias[tid] = g.bias[tid];
  {
    const int r = tid >> 1, part = tid & 1;
    const short8* src = (const short8*)(g.Xh + (size_t)(base+r)*128 + part*64);
    short8* dst = (short8*)(sA + r*KP_ + part*64);
    #pragma unroll
    for (int k=0;k<8;k++) dst[k] = src[k];
  }
  __syncthreads();
  const int lane = tid & 63, wv = tid >> 6;
  const int lane15 = lane & 15, quad = lane >> 4;
  const int n0 = wv * 32;
  f32x4 acc[8][2];
  #pragma unroll
  for (int mt=0; mt<8; mt++){ acc[mt][0]=(f32x4)0.f; acc[mt][1]=(f32x4)0.f; }
  const unsigned short* aptr = sA + lane15*KP_ + quad*8;
  const unsigned short* bptr = sW + (size_t)(n0 + lane15)*KP_ + quad*8;
  #pragma unroll
  for (int kk=0; kk<4; kk++){
    short8 af[8], bf2v[2];
    #pragma unroll
    for (int mt=0; mt<8; mt++) af[mt] = *(const short8*)(aptr + mt*16*KP_ + kk*32);
    bf2v[0] = *(const short8*)(bptr + kk*32);
    bf2v[1] = *(const short8*)(bptr + 16*KP_ + kk*32);
    #pragma unroll
    for (int mt=0; mt<8; mt++){
      acc[mt][0] = __builtin_amdgcn_mfma_f32_16x16x32_bf16(af[mt], bf2v[0], acc[mt][0], 0,0,0);
      acc[mt][1] = __builtin_amdgcn_mfma_f32_16x16x32_bf16(af[mt], bf2v[1], acc[mt][1], 0,0,0);
    }
  }
  __syncthreads();
  #pragma unroll
  for (int mt=0; mt<8; mt++){
    #pragma unroll
    for (int nt=0; nt<2; nt++){
      int col = n0 + nt*16 + lane15;
      float bsv = sbias[col];
      #pragma unroll
      for (int r4=0; r4<4; r4++){
        int row = mt*16 + quad*4 + r4;
        sA[row*KP_ + col] = f2bf((acc[mt][nt][r4] + bsv) * g.oscale);
      }
    }
  }
  __syncthreads();
  for (int i = tid; i < 2048; i += 256){
    int row = i >> 4, seg = i & 15;
    int rrow = base + row;
    size_t orow = g.outmode ? remap_kv(rrow, g.outmode) : (size_t)rrow;
    *(short8*)(g.OUTH + orow*128 + seg*8) = *(const short8*)&sA[row*KP_ + seg*8];
  }
}

// ---------------- fused tail (P-proj+skip+LN+MA+gelu+MB [+finalLN]) ---------
__global__ __launch_bounds__(256) void k_tail(
    const unsigned short* __restrict__ AOh,
    const float* __restrict__ skipf, int skipmode,
    const unsigned short* __restrict__ WtP, const float* __restrict__ abp,
    const float* __restrict__ png, const float* __restrict__ pnb,
    const unsigned short* __restrict__ WtMAa, const unsigned short* __restrict__ WtMAb,
    const float* __restrict__ bma,
    const unsigned short* __restrict__ WtMBa, const unsigned short* __restrict__ WtMBb,
    const float* __restrict__ bmb,
    float* __restrict__ Q1out, unsigned short* __restrict__ Q1n,
    const float* __restrict__ postg, const float* __restrict__ postb,
    float* __restrict__ out){
  constexpr int KP_ = 136;
  __shared__ unsigned short sW[128*KP_];
  __shared__ unsigned short sX[32*KP_];
  __shared__ unsigned short sH1[32*KP_];
  __shared__ unsigned short sH2[32*KP_];
  __shared__ float sCUR[32*132];
  __shared__ float sbias[128];
  __shared__ float sg[128], sb2[128];
  __shared__ float sMean[32], sRstd[32];
  const int tid = threadIdx.x;
  const int base = blockIdx.x * 32;
  const int lane = tid & 63, wv = tid >> 6;
  const int lane15 = lane & 15, quad = lane >> 4;
  const int n0 = wv * 32;

  auto loadW = [&](const unsigned short* Wp){
    for (int i = tid; i < 2048; i += 256){
      int n = i >> 4, k8 = (i & 15) << 3;
      *(short8*)&sW[n*KP_ + k8] = *(const short8*)(Wp + (size_t)n*128 + k8);
    }
  };
  auto domfma = [&](const unsigned short* Asrc, f32x4 acc[2][2]){
    const unsigned short* aptr = Asrc + lane15*KP_ + quad*8;
    const unsigned short* bptr = sW + (size_t)(n0 + lane15)*KP_ + quad*8;
    #pragma unroll
    for (int kk=0; kk<4; kk++){
      short8 a0 = *(const short8*)(aptr + kk*32);
      short8 a1 = *(const short8*)(aptr + 16*KP_ + kk*32);
      short8 b0 = *(const short8*)(bptr + kk*32);
      short8 b1 = *(const short8*)(bptr + 16*KP_ + kk*32);
      acc[0][0] = __builtin_amdgcn_mfma_f32_16x16x32_bf16(a0,b0,acc[0][0],0,0,0);
      acc[1][0] = __builtin_amdgcn_mfma_f32_16x16x32_bf16(a1,b0,acc[1][0],0,0,0);
      acc[0][1] = __builtin_amdgcn_mfma_f32_16x16x32_bf16(a0,b1,acc[0][1],0,0,0);
      acc[1][1] = __builtin_amdgcn_mfma_f32_16x16x32_bf16(a1,b1,acc[1][1],0,0,0);
    }
  };

  loadW(WtP);
  {
    const int r = tid >> 3, part = tid & 7;
    const short8* src = (const short8*)(AOh + (size_t)(base+r)*128 + part*16);
    short8* dst = (short8*)(sX + r*KP_ + part*16);
    dst[0] = src[0]; dst[1] = src[1];
  }
  if (tid < 128){ sbias[tid] = abp[tid]; sg[tid] = png[tid]; sb2[tid] = pnb[tid]; }
  __syncthreads();
  {
    f32x4 acc[2][2];
    acc[0][0]=(f32x4)0.f; acc[0][1]=(f32x4)0.f;
    acc[1][0]=(f32x4)0.f; acc[1][1]=(f32x4)0.f;
    domfma(sX, acc);
    #pragma unroll
    for (int mt=0; mt<2; mt++)
      #pragma unroll
      for (int nt=0; nt<2; nt++){
        int col = n0 + nt*16 + lane15;
        float bsv = sbias[col];
        #pragma unroll
        for (int r4=0; r4<4; r4++){
          int row = mt*16 + quad*4 + r4;
          int rrow = base + row;
          float v = acc[mt][nt][r4] + bsv;
          if (skipmode == 1){
            int bb = rrow >> 12, l = (rrow >> 6) & 63, pp = rrow & 63;
            int pix = (((l>>3)*8 + (pp>>3)) << 6) + (l&7)*8 + (pp&7);
            v += skipf[(size_t)bb*524288 + (size_t)col*4096 + pix];
          } else {
            v += skipf[(size_t)rrow*128 + col];
          }
          sCUR[row*132 + col] = v;
        }
      }
  }
  __syncthreads();
  loadW(WtMAa);
  if (tid < 128) sbias[tid] = bma[tid];
  {
    const int r = tid >> 3, part = tid & 7;
    float v[16];
    #pragma unroll
    for (int k=0;k<16;k++) v[k] = sCUR[r*132 + part*16 + k];
    float s=0.f, s2=0.f;
    #pragma unroll
    for (int k=0;k<16;k++){ s += v[k]; s2 = fmaf(v[k],v[k],s2); }
    #pragma unroll
    for (int off=4; off>0; off>>=1){ s += __shfl_xor(s, off, 8); s2 += __shfl_xor(s2, off, 8); }
    float mean = s*(1.f/128.f);
    float rstd = rsqrtf(fmaxf(s2*(1.f/128.f) - mean*mean, 0.f) + 1e-5f);
    #pragma unroll
    for (int k=0;k<16;k++){
      int c = part*16 + k;
      v[k] = fmaf((v[k]-mean)*rstd, sg[c], sb2[c]);
    }
    store_bf16x8(sX + r*KP_ + part*16, v);
    store_bf16x8(sX + r*KP_ + part*16 + 8, v+8);
  }
  __syncthreads();
  {
    f32x4 acc[2][2];
    acc[0][0]=(f32x4)0.f; acc[0][1]=(f32x4)0.f;
    acc[1][0]=(f32x4)0.f; acc[1][1]=(f32x4)0.f;
    domfma(sX, acc);
    #pragma unroll
    for (int mt=0; mt<2; mt++)
      #pragma unroll
      for (int nt=0; nt<2; nt++){
        int col = n0 + nt*16 + lane15;
        float bsv = sbias[col];
        #pragma unroll
        for (int r4=0; r4<4; r4++){
          int row = mt*16 + quad*4 + r4;
          sH1[row*KP_ + col] = f2bf(gelu_erf(acc[mt][nt][r4] + bsv));
        }
      }
  }
  __syncthreads();
  loadW(WtMAb);
  if (tid < 128) sbias[tid] = bma[128 + tid];
  __syncthreads();
  {
    f32x4 acc[2][2];
    acc[0][0]=(f32x4)0.f; acc[0][1]=(f32x4)0.f;
    acc[1][0]=(f32x4)0.f; acc[1][1]=(f32x4)0.f;
    domfma(sX, acc);
    #pragma unroll
    for (int mt=0; mt<2; mt++)
      #pragma unroll
      for (int nt=0; nt<2; nt++){
        int col = n0 + nt*16 + lane15;
        float bsv = sbias[col];
        #pragma unroll
        for (int r4=0; r4<4; r4++){
          int row = mt*16 + quad*4 + r4;
          sH2[row*KP_ + col] = f2bf(gelu_erf(acc[mt][nt][r4] + bsv));
        }
      }
  }
  __syncthreads();
  loadW(WtMBa);
  if (tid < 128) sbias[tid] = bmb[tid];
  __syncthreads();
  f32x4 acc[2][2];
  acc[0][0]=(f32x4)0.f; acc[0][1]=(f32x4)0.f;
  acc[1][0]=(f32x4)0.f; acc[1][1]=(f32x4)0.f;
  domfma(sH1, acc);
  __syncthreads();
  loadW(WtMBb);
  __syncthreads();
  domfma(sH2, acc);
  if (out == nullptr){
    // stage 1: Q1 fp32 out + pre-normalized Q1n bf16 (affine folded into WtQ2)
    #pragma unroll
    for (int mt=0; mt<2; mt++)
      #pragma unroll
      for (int nt=0; nt<2; nt++){
        int col = n0 + nt*16 + lane15;
        float bsv = sbias[col];
        #pragma unroll
        for (int r4=0; r4<4; r4++){
          int row = mt*16 + quad*4 + r4;
          float v = acc[mt][nt][r4] + bsv + sCUR[row*132 + col];
          sCUR[row*132 + col] = v;
          Q1out[(size_t)(base+row)*128 + col] = v;
        }
      }
    __syncthreads();
    {
      const int r = tid >> 3, part = tid & 7;
      float s=0.f, s2=0.f;
      #pragma unroll
      for (int k=0;k<16;k++){
        float v = sCUR[r*132 + part*16 + k];
        s += v; s2 = fmaf(v,v,s2);
      }
      #pragma unroll
      for (int off=4; off>0; off>>=1){ s += __shfl_xor(s, off, 8); s2 += __shfl_xor(s2, off, 8); }
      if (part == 0){
        float mean = s*(1.f/128.f);
        sMean[r] = mean;
        sRstd[r] = rsqrtf(fmaxf(s2*(1.f/128.f) - mean*mean, 0.f) + 1e-5f);
      }
    }
    __syncthreads();
    for (int i = tid; i < 512; i += 256){
      int row = i >> 4, seg = i & 15;
      float mean = sMean[row], rstd = sRstd[row];
      float v[8];
      #pragma unroll
      for (int k=0;k<8;k++) v[k] = (sCUR[row*132 + seg*8 + k] - mean)*rstd;
      store_bf16x8(Q1n + (size_t)(base+row)*128 + seg*8, v);
    }
  } else {
    float res[2][2][4];
    #pragma unroll
    for (int mt=0; mt<2; mt++)
      #pragma unroll
      for (int nt=0; nt<2; nt++){
        int col = n0 + nt*16 + lane15;
        float bsv = sbias[col];
        #pragma unroll
        for (int r4=0; r4<4; r4++){
          int row = mt*16 + quad*4 + r4;
          res[mt][nt][r4] = acc[mt][nt][r4] + bsv + sCUR[row*132 + col];
        }
      }
    __syncthreads();
    #pragma unroll
    for (int mt=0; mt<2; mt++)
      #pragma unroll
      for (int nt=0; nt<2; nt++){
        int col = n0 + nt*16 + lane15;
        #pragma unroll
        for (int r4=0; r4<4; r4++){
          int row = mt*16 + quad*4 + r4;
          sCUR[row*132 + col] = res[mt][nt][r4];
        }
      }
    __syncthreads();
    {
      const int r = tid >> 3, part = tid & 7;
      float s=0.f, s2=0.f;
      #pragma unroll
      for (int k=0;k<16;k++){
        float v = sCUR[r*132 + part*16 + k];
        s += v; s2 = fmaf(v,v,s2);
      }
      #pragma unroll
      for (int off=4; off>0; off>>=1){ s += __shfl_xor(s, off, 8); s2 += __shfl_xor(s2, off, 8); }
      if (part == 0){
        float mean = s*(1.f/128.f);
        sMean[r] = mean;
        sRstd[r] = rsqrtf(fmaxf(s2*(1.f/128.f) - mean*mean, 0.f) + 1e-5f);
      }
    }
    __syncthreads();
    {
      int c = tid & 127, half = tid >> 7;
      int b = base >> 12, l = (base >> 6) & 63, p0 = base & 63;
      float go = postg[c], bo = postb[c];
      #pragma unroll
      for (int seg=0; seg<2; seg++){
        int p = p0 + half*16 + seg*8;
        int hrow = (l>>3)*8 + (p>>3);
        int w0 = (l&7)*8;
        float rr[8];
        #pragma unroll
        for (int j=0;j<8;j++){
          int row = half*16 + seg*8 + j;
          rr[j] = fmaf((sCUR[row*132 + c] - sMean[row])*sRstd[row], go, bo);
        }
        size_t obase = ((size_t)(b*128 + c))*4096 + (size_t)hrow*64 + w0;
        *(float4*)&out[obase]   = make_float4(rr[0],rr[1],rr[2],rr[3]);
        *(float4*)&out[obase+4] = make_float4(rr[4],rr[5],rr[6],rr[7]);
      }
    }
  }
}

// ---------------- MFMA attention (unchanged) --------------------------------
__global__ __launch_bounds__(256) void k_attn2(const unsigned short* __restrict__ QPh,
    const unsigned short* __restrict__ KPh, const unsigned short* __restrict__ VPh,
    unsigned short* __restrict__ AOh, int nrep, int nQ){
  __shared__ unsigned short Ksh[288*40];
  __shared__ unsigned short Vt[32*296];
  __shared__ unsigned short Psh[4*16*40];
  __shared__ float rs[4*16];
  int hd = blockIdx.x & 3; int bl = blockIdx.x >> 2;
  size_t kvbase = (size_t)bl*264;
  int tid = threadIdx.x;
  for (int idx = tid; idx < 1056; idx += 256){
    int row = idx >> 2, seg = idx & 3;
    *(short8*)&Ksh[row*40 + seg*8] =
      *(const short8*)(KPh + (kvbase+row)*128 + hd*32 + seg*8);
  }
  for (int idx = tid; idx < 96; idx += 256){
    int row = 264 + (idx>>2), seg = idx & 3;
    short8 z = {0,0,0,0,0,0,0,0};
    *(short8*)&Ksh[row*40 + seg*8] = z;
  }
  for (int idx = tid; idx < 1056; idx += 256){
    int row = idx >> 2, seg = idx & 3;
    union { short8 s; unsigned short u[8]; } t;
    t.s = *(const short8*)(VPh + (kvbase+row)*128 + hd*32 + seg*8);
    #pragma unroll
    for (int i=0;i<8;i++) Vt[(seg*8+i)*296 + row] = t.u[i];
  }
  for (int idx = tid; idx < 384; idx += 256){
    int d = idx / 12, kp = 264 + (idx % 12)*2;
    *(unsigned*)&Vt[d*296 + kp] = 0u;
  }
  __syncthreads();
  const int wv = tid >> 6, lane = tid & 63;
  const int lane15 = lane & 15, quad = lane >> 4;
  unsigned short* Pw = Psh + wv*640;
  float* rsw = rs + wv*16;
  short8 vfrag[9][2];
  #pragma unroll
  for (int kc=0; kc<9; kc++){
    vfrag[kc][0] = *(const short8*)&Vt[(lane15)*296      + kc*32 + quad*8];
    vfrag[kc][1] = *(const short8*)&Vt[(16+lane15)*296   + kc*32 + quad*8];
  }
  f32x4 macc0 = (f32x4)0.f, macc1 = (f32x4)0.f;
  for (int cam = 0; cam < nrep; cam++){
    int qrow = bl*nQ + (cam*4 + wv)*16 + lane15;
    short8 qf = *(const short8*)(QPh + (size_t)qrow*128 + hd*32 + quad*8);
    f32x4 oa0 = (f32x4)0.f, oa1 = (f32x4)0.f;
    float rsum = 0.f;
    #pragma unroll
    for (int kc=0; kc<9; kc++){
      #pragma unroll
      for (int sub=0; sub<2; sub++){
        int kt = kc*2 + sub;
        short8 kf = *(const short8*)&Ksh[(kt*16 + lane15)*40 + quad*8];
        f32x4 st = __builtin_amdgcn_mfma_f32_16x16x32_bf16(kf, qf, (f32x4)0.f, 0,0,0);
        int kbase = kt*16 + quad*4;
        float e0 = (kbase+0 < 264) ? __expf(st[0]) : 0.f;
        float e1 = (kbase+1 < 264) ? __expf(st[1]) : 0.f;
        float e2 = (kbase+2 < 264) ? __expf(st[2]) : 0.f;
        float e3 = (kbase+3 < 264) ? __expf(st[3]) : 0.f;
        rsum += (e0+e1)+(e2+e3);
        uint2 pk;
        pk.x = (unsigned)f2bf(e0) | ((unsigned)f2bf(e1) << 16);
        pk.y = (unsigned)f2bf(e2) | ((unsigned)f2bf(e3) << 16);
        *(uint2*)&Pw[lane15*40 + sub*16 + quad*4] = pk;
      }
      short8 pf = *(const short8*)&Pw[lane15*40 + quad*8];
      oa0 = __builtin_amdgcn_mfma_f32_16x16x32_bf16(pf, vfrag[kc][0], oa0, 0,0,0);
      oa1 = __builtin_amdgcn_mfma_f32_16x16x32_bf16(pf, vfrag[kc][1], oa1, 0,0,0);
    }
    rsum += __shfl_xor(rsum, 16);
    rsum += __shfl_xor(rsum, 32);
    if (lane < 16) rsw[lane] = rsum;
    f32x4 rv = *(f32x4*)&rsw[quad*4];
    #pragma unroll
    for (int r=0;r<4;r++){
      float inv = 1.f / rv[r];
      macc0[r] = fmaf(oa0[r], inv, macc0[r]);
      macc1[r] = fmaf(oa1[r], inv, macc1[r]);
    }
  }
  float sc = (nrep == 6) ? (1.f/6.f) : 1.f;
  int pixb = wv*16 + quad*4;
  #pragma unroll
  for (int r=0;r<4;r++){
    size_t rowo = ((size_t)(bl*64 + pixb + r))*128 + hd*32;
    AOh[rowo + lane15]      = f2bf(macc0[r]*sc);
    AOh[rowo + 16 + lane15] = f2bf(macc1[r]*sc);
  }
}

extern "C" void kernel_launch(void* const* d_in, const int* in_sizes, int n_in,
                              void* d_out, int out_size, void* d_ws, size_t ws_size,
                              hipStream_t stream) {
  (void)in_sizes; (void)n_in; (void)out_size; (void)ws_size;
  const float* x     = (const float*)d_in[1];
  const float* gridp = (const float*)d_in[2];
  const float* feat  = (const float*)d_in[3];
  const float* Iinv  = (const float*)d_in[4];
  const float* Einv  = (const float*)d_in[5];
  const float* gfl   = (const float*)d_in[6];
  const float* bfl   = (const float*)d_in[7];
  const float* Wfl   = (const float*)d_in[8];
  const float* gfp   = (const float*)d_in[9];
  const float* bfp   = (const float*)d_in[10];
  const float* Wfp   = (const float*)d_in[11];
  const float* Wbev  = (const float*)d_in[12];
  const float* bbev  = (const float*)d_in[13];
  const float* Wimg  = (const float*)d_in[14];
  const float* Wcam  = (const float*)d_in[15];
  const float* alng  = (const float*)d_in[16];
  const float* alnb  = (const float*)d_in[17];
  const float* aWqkv = (const float*)d_in[18];
  const float* abqkv = (const float*)d_in[19];
  const float* aWp   = (const float*)d_in[20];
  const float* abp   = (const float*)d_in[21];
  const float* png   = (const float*)d_in[22];
  const float* pnb   = (const float*)d_in[23];
  const float* Wma   = (const float*)d_in[24];
  const float* bma   = (const float*)d_in[25];
  const float* Wmb   = (const float*)d_in[26];
  const float* bmb   = (const float*)d_in[27];
  const float* postg = (const float*)d_in[28];
  const float* postb = (const float*)d_in[29];
  float* out = (float*)d_out;
  float* ws  = (float*)d_ws;
  const float QSC = 0.17677669529663687f;

  float* biasP = ws;                                   // 768 fp32
  unsigned short* Wt  = (unsigned short*)(ws + 2048);
  unsigned short* K1h = (unsigned short*)(ws + 149504);
  unsigned short* V1h = K1h + 4325376;
  unsigned short* KPh = V1h + 4325376;
  unsigned short* VPh = KPh + 4325376;
  unsigned short* QPh = VPh + 4325376;
  unsigned short* Qbh = QPh + 6291456;
  unsigned short* AOh = Qbh + 6291456;
  float* Q1f = (float*)(AOh + 1048576);                // 8192x128 fp32
  unsigned short* Q1n = (unsigned short*)(Q1f + 1048576);

  unsigned short* WtQ1 = Wt;            unsigned short* WtK1 = Wt + 16384;
  unsigned short* WtV1 = Wt + 32768;    unsigned short* WtQ2 = Wt + 49152;
  unsigned short* WtK2 = Wt + 65536;    unsigned short* WtV2 = Wt + 81920;
  unsigned short* WtP1 = Wt + 98304;    unsigned short* WtP2 = Wt + 114688;
  unsigned short* WtMA1 = Wt + 131072;  unsigned short* WtMA2 = Wt + 163840;
  unsigned short* WtMB1a = Wt + 196608; unsigned short* WtMB1b = Wt + 212992;
  unsigned short* WtMB2a = Wt + 229376; unsigned short* WtMB2b = Wt + 245760;
  unsigned short* WtFL = Wt + 262144;   unsigned short* WtFP = Wt + 278528;

  // 1) fused prep (wprep 64 | bias-fold 6 | geom 4224 | bevq 1024)
  k_prep<<<5318, 128, 0, stream>>>(aWqkv, aWp, Wma, Wmb, Wfl, Wfp, Wt,
      Iinv, Einv, Wimg, Wcam, K1h, gridp, Wbev, bbev, x, alng, alnb,
      abqkv, biasP, Qbh);

  // 2) conv K+V + row-normalize -> K1n/V1n (in place)
  k_conv<<<528, 256, 0, stream>>>(feat, gfp, bfp, WtFP, K1h,
                                  gfl, bfl, WtFL, V1h);

  // 3) stage-1 Q+K+V projections (pure GEMMs)
  {
    GArg q{Qbh, WtQ1, biasP,      QPh, QSC, 0};
    GArg kk{K1h, WtK1, biasP+128, KPh, 1.f, 1};
    GArg vv{V1h, WtV1, biasP+256, VPh, 1.f, 1};
    k_qkv<<<912, 256, 0, stream>>>(q, kk, vv, 384, 648);
  }
  // 4) stage-1 attention
  k_attn2<<<512, 256, 0, stream>>>(QPh, KPh, VPh, AOh, 6, 384);
  // 5) stage-1 tail -> Q1f fp32 + Q1n bf16
  k_tail<<<256, 256, 0, stream>>>(AOh, x, 1, WtP1, abp, png, pnb,
      WtMA1, WtMA1+16384, bma, WtMB1a, WtMB1b, bmb, Q1f, Q1n,
      nullptr, nullptr, nullptr);
  // 6) stage-2 Q+K+V projections
  {
    GArg q{Q1n, WtQ2, biasP+384,  QPh, QSC, 0};
    GArg kk{K1h, WtK2, biasP+512, KPh, 1.f, 2};
    GArg vv{V1h, WtV2, biasP+640, VPh, 1.f, 2};
    k_qkv<<<592, 256, 0, stream>>>(q, kk, vv, 64, 328);
  }
  // 7) stage-2 attention
  k_attn2<<<512, 256, 0, stream>>>(QPh, KPh, VPh, AOh, 1, 64);
  // 8) stage-2 tail (+final LN) -> out
  k_tail<<<256, 256, 0, stream>>>(AOh, Q1f, 3, WtP2, abp+128, png+128, pnb+128,
      WtMA2, WtMA2+16384, bma+256, WtMB2a, WtMB2b, bmb+128, nullptr, nullptr,
      postg, postb, out);
}

// Round 11
// 273.104 us; speedup vs baseline: 1.0215x; 1.0215x over previous
//
#include <hip/hip_runtime.h>
#include <math.h>

// CrossViewSwapAttention forward. Round 11: dependency-graph consolidation.
// QKV5: stage-1 Q/K/V + stage-2 K/V in ONE dispatch (stage-2 KV depends only
// on conv output); stage-2 Q projection fused into tail1 (row-local, uses the
// normalized Q1 already in LDS); attn V-staging pair-packed. 7 dispatches.
// B=2 N=6 H=W=64 FH=32 FW=88 DIM=128 HEADS=4 DH=32 QW=8x8 KW=4x11

typedef __attribute__((ext_vector_type(8))) short short8;
typedef __attribute__((ext_vector_type(4))) float f32x4;

__device__ __forceinline__ unsigned short f2bf(float f){
  union { float f; unsigned u; } v; v.f = f;
  unsigned r = v.u + 0x7FFF + ((v.u >> 16) & 1);   // RNE
  return (unsigned short)(r >> 16);
}
__device__ __forceinline__ float bf2f(unsigned short h){
  union { unsigned u; float f; } v; v.u = ((unsigned)h) << 16; return v.f;
}
__device__ __forceinline__ void store_bf16x8(unsigned short* p, const float* v){
  union { short8 s8; unsigned short u[8]; } u;
  #pragma unroll
  for (int i=0;i<8;i++) u.u[i] = f2bf(v[i]);
  *(short8*)p = u.s8;
}

__device__ __forceinline__ float gelu_erf(float x){
  float z = x * 0.70710678118654752f;
  float a = fabsf(z);
  float t = 1.0f / fmaf(0.3275911f, a, 1.0f);
  float p = t*(0.254829592f + t*(-0.284496736f + t*(1.421413741f +
            t*(-1.453152027f + t*1.061405429f))));
  float er = 1.0f - p*__expf(-a*a);
  er = copysignf(er, z);
  return 0.5f * x * (1.0f + er);
}

__device__ __forceinline__ size_t remap_kv(int tok, int mode){
  int bn = tok / 2816; int p = tok - bn*2816;
  int b = bn / 6, n = bn - b*6;
  int i = p / 88, j = p - i*88;
  int l, t;
  if (mode == 1){
    int jw = j / 11;
    l = (i >> 2)*8 + jw;
    t = n*44 + (i & 3)*11 + (j - jw*11);
  } else {
    l = (i & 7)*8 + (j & 7);
    t = n*44 + (i >> 3)*11 + (j >> 3);
  }
  return (size_t)((b*64 + l)*264 + t);
}

// ---------------- fused prep: wprep(+g-fold) | bias-fold | geom | bevq ------
__global__ __launch_bounds__(128) void k_prep(
    const float* __restrict__ qkv, const float* __restrict__ wp,
    const float* __restrict__ wma, const float* __restrict__ wmb,
    const float* __restrict__ wfl, const float* __restrict__ wfp,
    unsigned short* __restrict__ Wt,
    const float* __restrict__ Iinv, const float* __restrict__ Einv,
    const float* __restrict__ Wimg, const float* __restrict__ Wcam,
    unsigned short* __restrict__ K1h,
    const float* __restrict__ gridp, const float* __restrict__ Wbev,
    const float* __restrict__ bbev, const float* __restrict__ x,
    const float* __restrict__ lg, const float* __restrict__ lb,
    const float* __restrict__ abqkv, float* __restrict__ biasP,
    unsigned short* __restrict__ Qh){
  __shared__ float sx[128][9];
  int bid = blockIdx.x;
  if (bid < 64){
    const int sel[16]  = {0,0,0,0,0,0, 1,1, 2,2, 3,3,3,3, 4,5};
    const int soff[16] = {0,16384,32768,49152,65536,81920, 0,16384, 0,32768,
                          0,16384,32768,49152, 0,0};
    const int doff[16] = {0,16384,32768,49152,65536,81920, 98304,114688,
                          131072,163840, 196608,212992,229376,245760, 262144,278528};
    const int Ns[16]   = {128,128,128,128,128,128, 128,128, 256,256,
                          128,128,128,128, 128,128};
    const int trs[16]  = {1,1,1,1,1,1, 1,1, 1,1, 1,1,1,1, 0,0};
    int sg = bid >> 2, q = bid & 3;
    const float* srcs[6] = {qkv, wp, wma, wmb, wfl, wfp};
    const float* src = srcs[sel[sg]] + soff[sg];
    unsigned short* dst = Wt + doff[sg];
    int K = 128, N = Ns[sg];
    int quarter = (K*N) >> 2;
    bool fold = (sg >= 1 && sg <= 5);       // K1,V1,Q2,K2,V2 qkv weights
    const float* gv = lg + sg*128;
    for (int idx = q*quarter + threadIdx.x; idx < (q+1)*quarter; idx += 128){
      int n = idx / K, k = idx - n*K;
      float v = trs[sg] ? src[k*N + n] : src[idx];
      if (fold) v *= gv[k];
      dst[idx] = f2bf(v);
    }
  } else if (bid < 70){
    // folded biases for the 6 qkv projections
    int m = bid - 64;
    int n = threadIdx.x;
    float s = abqkv[m*128 + n];
    if (m > 0){
      const float* lnb = lb + m*128;
      const float* W = qkv + m*16384;
      for (int k=0;k<128;k++) s = fmaf(lnb[k], W[k*128 + n], s);
    }
    biasP[m*128 + n] = s;
  } else if (bid < 4294){
    int tile = bid - 70;
    int bn = tile / 352; int p0 = (tile - bn*352)*8;
    int xid = threadIdx.x >> 4, part = threadIdx.x & 15;
    int p = p0 + xid;
    int i = p / 88, j = p - i*88;
    float xs = (float)j * (480.0f/87.0f);
    float ys = (float)i * (224.0f/31.0f);
    const float* I = Iinv + bn*9;
    const float* E = Einv + bn*16;
    float c0 = I[0]*xs + I[1]*ys + I[2];
    float c1 = I[3]*xs + I[4]*ys + I[5];
    float c2 = I[6]*xs + I[7]*ys + I[8];
    float d0 = E[0]*c0 + E[1]*c1 + E[2]*c2 + E[3];
    float d1 = E[4]*c0 + E[5]*c1 + E[6]*c2 + E[7];
    float d2 = E[8]*c0 + E[9]*c1 + E[10]*c2 + E[11];
    float d3 = E[12]*c0 + E[13]*c1 + E[14]*c2 + E[15];
    float v[8]; float sq = 0.f;
    #pragma unroll
    for (int k=0;k<8;k++){
      int o = part*8 + k;
      const float* W = Wimg + o*4;
      const float* Wc = Wcam + o*4;
      float de = W[0]*d0 + W[1]*d1 + W[2]*d2 + W[3]*d3;
      float ce = Wc[0]*E[3] + Wc[1]*E[7] + Wc[2]*E[11] + Wc[3]*E[15];
      float vv = de - ce;
      v[k] = vv; sq = fmaf(vv, vv, sq);
    }
    #pragma unroll
    for (int off=8; off>0; off>>=1) sq += __shfl_xor(sq, off, 16);
    float rn = 1.0f / fmaxf(sqrtf(sq), 1e-12f);
    float o8[8];
    #pragma unroll
    for (int k=0;k<8;k++) o8[k] = v[k]*rn;
    store_bf16x8(K1h + (size_t)(bn*2816 + p)*128 + part*8, o8);
  } else {
    int bid2 = bid - 4294;
    int b = bid2 >> 9; int pp0 = (bid2 & 511) << 3;
    {
      int cg = threadIdx.x >> 3, px = threadIdx.x & 7;
      #pragma unroll
      for (int i=0;i<8;i++){
        int c = cg + 16*i;
        sx[c][px] = x[(size_t)b*524288 + (size_t)c*4096 + pp0 + px];
      }
    }
    __syncthreads();
    int xid = threadIdx.x >> 4, part = threadIdx.x & 15;
    int pix = pp0 + xid;
    int h = pix >> 6, w = pix & 63;
    int l = (h>>3)*8 + (w>>3);
    int tq = (h&7)*8 + (w&7);
    float g0 = gridp[pix], g1 = gridp[4096 + pix];
    float we[8], xv[8];
    #pragma unroll
    for (int k=0;k<8;k++){
      int o = part*8 + k;
      we[k] = Wbev[o*2]*g0 + Wbev[o*2+1]*g1 + bbev[o];
      xv[k] = sx[part*8+k][xid];
    }
    for (int n=0; n<6; n++){
      const float* E = Einv + (b*6+n)*16;
      float v[8]; float sq = 0.f;
      #pragma unroll
      for (int k=0;k<8;k++){
        int o = part*8 + k;
        const float* Wc = Wcam + o*4;
        float ce = Wc[0]*E[3] + Wc[1]*E[7] + Wc[2]*E[11] + Wc[3]*E[15];
        float vv = we[k] - ce;
        v[k] = vv; sq = fmaf(vv, vv, sq);
      }
      #pragma unroll
      for (int off=8; off>0; off>>=1) sq += __shfl_xor(sq, off, 16);
      float rn = 1.0f / fmaxf(sqrtf(sq), 1e-12f);
      float q[8]; float s=0.f, s2=0.f;
      #pragma unroll
      for (int k=0;k<8;k++){
        q[k] = fmaf(v[k], rn, xv[k]);
        s += q[k]; s2 = fmaf(q[k], q[k], s2);
      }
      #pragma unroll
      for (int off=8; off>0; off>>=1){ s += __shfl_xor(s, off, 16); s2 += __shfl_xor(s2, off, 16); }
      float mean = s*(1.f/128.f);
      float rstd = rsqrtf(fmaxf(s2*(1.f/128.f) - mean*mean, 0.f) + 1e-5f);
      size_t row = (size_t)((b*64 + l)*384 + n*64 + tq);
      float o8[8];
      #pragma unroll
      for (int k=0;k<8;k++){
        int c = part*8 + k;
        o8[k] = fmaf((q[k]-mean)*rstd, lg[c], lb[c]);
      }
      store_bf16x8(Qh + row*128 + part*8, o8);
    }
  }
}

// ---------------- conv + row-normalize (emits K1n/V1n), MT=128 --------------
__global__ __launch_bounds__(256) void k_conv(const float* __restrict__ feat,
    const float* __restrict__ gK, const float* __restrict__ bK,
    const unsigned short* __restrict__ WK, unsigned short* __restrict__ K1h,
    const float* __restrict__ gV, const float* __restrict__ bV,
    const unsigned short* __restrict__ WV, unsigned short* __restrict__ V1h){
  constexpr int KP_ = 136;
  __shared__ unsigned short sW[128*KP_];
  __shared__ unsigned short sA[128*KP_];
  __shared__ float sg[128], sb[128];
  __shared__ float sMean[128], sRstd[128];
  const int which = (blockIdx.x >= 264);
  const int bid = which ? blockIdx.x - 264 : blockIdx.x;
  const float* gg = which ? gV : gK;
  const float* bb = which ? bV : bK;
  const unsigned short* Wts = which ? WV : WK;
  unsigned short* OUT = which ? V1h : K1h;
  const int tid = threadIdx.x;
  const int base = bid * 128;
  for (int i = tid; i < 2048; i += 256){
    int n = i >> 4, k8 = (i & 15) << 3;
    *(short8*)&sW[n*KP_ + k8] = *(const short8*)(Wts + (size_t)n*128 + k8);
  }
  if (tid < 128){ sg[tid]=gg[tid]; sb[tid]=bb[tid]; }
  const float RSQ = rsqrtf(1.0f + 1e-5f);
  {
    int prow = tid & 127, cseg = tid >> 7;
    int bn = base / 2816;
    int p = base - bn*2816 + prow;
    const float* fb = feat + ((size_t)bn*128 + cseg*64)*2816 + p;
    #pragma unroll 8
    for (int i=0;i<64;i+=2){
      int c = cseg*64 + i;
      float t0 = fb[(size_t)i*2816] * RSQ;
      float t1 = fb[(size_t)(i+1)*2816] * RSQ;
      float y0 = fmaxf(fmaf(t0, sg[c],   sb[c]),   0.f);
      float y1 = fmaxf(fmaf(t1, sg[c+1], sb[c+1]), 0.f);
      unsigned u = (unsigned)f2bf(y0) | ((unsigned)f2bf(y1) << 16);
      *(unsigned*)&sA[prow*KP_ + c] = u;
    }
  }
  __syncthreads();
  const int lane = tid & 63, wv = tid >> 6;
  const int lane15 = lane & 15, quad = lane >> 4;
  const int n0 = wv * 32;
  f32x4 acc[8][2];
  #pragma unroll
  for (int mt=0; mt<8; mt++){ acc[mt][0]=(f32x4)0.f; acc[mt][1]=(f32x4)0.f; }
  const unsigned short* aptr = sA + lane15*KP_ + quad*8;
  const unsigned short* bptr = sW + (size_t)(n0 + lane15)*KP_ + quad*8;
  #pragma unroll
  for (int kk=0; kk<4; kk++){
    short8 af[8], bf2v[2];
    #pragma unroll
    for (int mt=0; mt<8; mt++) af[mt] = *(const short8*)(aptr + mt*16*KP_ + kk*32);
    bf2v[0] = *(const short8*)(bptr + kk*32);
    bf2v[1] = *(const short8*)(bptr + 16*KP_ + kk*32);
    #pragma unroll
    for (int mt=0; mt<8; mt++){
      acc[mt][0] = __builtin_amdgcn_mfma_f32_16x16x32_bf16(af[mt], bf2v[0], acc[mt][0], 0,0,0);
      acc[mt][1] = __builtin_amdgcn_mfma_f32_16x16x32_bf16(af[mt], bf2v[1], acc[mt][1], 0,0,0);
    }
  }
  __syncthreads();
  #pragma unroll
  for (int mt=0; mt<8; mt++){
    #pragma unroll
    for (int nt=0; nt<2; nt++){
      int col = n0 + nt*16 + lane15;
      #pragma unroll
      for (int r4=0; r4<4; r4++){
        int row = mt*16 + quad*4 + r4;
        float v = acc[mt][nt][r4];
        if (!which) v += bf2f(K1h[(size_t)(base+row)*128 + col]);   // + geom
        sA[row*KP_ + col] = f2bf(v);
      }
    }
  }
  __syncthreads();
  {
    int r = tid >> 1, part = tid & 1;
    float s=0.f, s2=0.f;
    #pragma unroll 8
    for (int k=0;k<64;k++){
      float v = bf2f(sA[r*KP_ + part*64 + k]);
      s += v; s2 = fmaf(v,v,s2);
    }
    s += __shfl_xor(s, 1); s2 += __shfl_xor(s2, 1);
    if (part == 0){
      float mean = s*(1.f/128.f);
      sMean[r] = mean;
      sRstd[r] = rsqrtf(fmaxf(s2*(1.f/128.f) - mean*mean, 0.f) + 1e-5f);
    }
  }
  __syncthreads();
  for (int i = tid; i < 2048; i += 256){
    int row = i >> 4, seg = i & 15;
    float mean = sMean[row], rstd = sRstd[row];
    union { short8 s; unsigned short u[8]; } t;
    t.s = *(const short8*)&sA[row*KP_ + seg*8];
    float v[8];
    #pragma unroll
    for (int k=0;k<8;k++) v[k] = (bf2f(t.u[k]) - mean)*rstd;
    store_bf16x8(OUT + (size_t)(base+row)*128 + seg*8, v);
  }
}

// ---------------- 5-role pure bf16 GEMM, MT=128 -----------------------------
struct GArg {
  const unsigned short* Xh;
  const unsigned short* Wt; const float* bias;
  unsigned short* OUTH; float oscale; int outmode;
};
struct G5 { GArg g[5]; int s[4]; };

__global__ __launch_bounds__(256) void k_qkv5(G5 A){
  constexpr int KP_ = 136;
  __shared__ unsigned short sW[128*KP_];
  __shared__ unsigned short sA[128*KP_];
  __shared__ float sbias[128];
  const int b0 = (int)blockIdx.x;
  const int ridx = (b0 < A.s[0]) ? 0 : (b0 < A.s[1]) ? 1 : (b0 < A.s[2]) ? 2
                 : (b0 < A.s[3]) ? 3 : 4;
  const GArg g = A.g[ridx];
  const int bid = b0 - (ridx ? A.s[ridx-1] : 0);
  const int base = bid * 128;
  const int tid = threadIdx.x;
  for (int i = tid; i < 2048; i += 256){
    int n = i >> 4, k8 = (i & 15) << 3;
    *(short8*)&sW[n*KP_ + k8] = *(const short8*)(g.Wt + (size_t)n*128 + k8);
  }
  if (tid < 128) sbias[tid] = g.bias[tid];
  {
    const int r = tid >> 1, part = tid & 1;
    const short8* src = (const short8*)(g.Xh + (size_t)(base+r)*128 + part*64);
    short8* dst = (short8*)(sA + r*KP_ + part*64);
    #pragma unroll
    for (int k=0;k<8;k++) dst[k] = src[k];
  }
  __syncthreads();
  const int lane = tid & 63, wv = tid >> 6;
  const int lane15 = lane & 15, quad = lane >> 4;
  const int n0 = wv * 32;
  f32x4 acc[8][2];
  #pragma unroll
  for (int mt=0; mt<8; mt++){ acc[mt][0]=(f32x4)0.f; acc[mt][1]=(f32x4)0.f; }
  const unsigned short* aptr = sA + lane15*KP_ + quad*8;
  const unsigned short* bptr = sW + (size_t)(n0 + lane15)*KP_ + quad*8;
  #pragma unroll
  for (int kk=0; kk<4; kk++){
    short8 af[8], bf2v[2];
    #pragma unroll
    for (int mt=0; mt<8; mt++) af[mt] = *(const short8*)(aptr + mt*16*KP_ + kk*32);
    bf2v[0] = *(const short8*)(bptr + kk*32);
    bf2v[1] = *(const short8*)(bptr + 16*KP_ + kk*32);
    #pragma unroll
    for (int mt=0; mt<8; mt++){
      acc[mt][0] = __builtin_amdgcn_mfma_f32_16x16x32_bf16(af[mt], bf2v[0], acc[mt][0], 0,0,0);
      acc[mt][1] = __builtin_amdgcn_mfma_f32_16x16x32_bf16(af[mt], bf2v[1], acc[mt][1], 0,0,0);
    }
  }
  __syncthreads();
  #pragma unroll
  for (int mt=0; mt<8; mt++){
    #pragma unroll
    for (int nt=0; nt<2; nt++){
      int col = n0 + nt*16 + lane15;
      float bsv = sbias[col];
      #pragma unroll
      for (int r4=0; r4<4; r4++){
        int row = mt*16 + quad*4 + r4;
        sA[row*KP_ + col] = f2bf((acc[mt][nt][r4] + bsv) * g.oscale);
      }
    }
  }
  __syncthreads();
  for (int i = tid; i < 2048; i += 256){
    int row = i >> 4, seg = i & 15;
    int rrow = base + row;
    size_t orow = g.outmode ? remap_kv(rrow, g.outmode) : (size_t)rrow;
    *(short8*)(g.OUTH + orow*128 + seg*8) = *(const short8*)&sA[row*KP_ + seg*8];
  }
}

// ---------------- fused tail: P+skip+LN+MA+gelu+MB, then (stage1) q2-proj
// or (stage2) final LN + transposed store.
__global__ __launch_bounds__(256) void k_tail(
    const unsigned short* __restrict__ AOh,
    const float* __restrict__ skipf, int skipmode,
    const unsigned short* __restrict__ WtP, const float* __restrict__ abp,
    const float* __restrict__ png, const float* __restrict__ pnb,
    const unsigned short* __restrict__ WtMAa, const unsigned short* __restrict__ WtMAb,
    const float* __restrict__ bma,
    const unsigned short* __restrict__ WtMBa, const unsigned short* __restrict__ WtMBb,
    const float* __restrict__ bmb,
    float* __restrict__ Q1out,
    const unsigned short* __restrict__ WtQ2, const float* __restrict__ q2bias,
    float q2scale, unsigned short* __restrict__ QPout,
    const float* __restrict__ postg, const float* __restrict__ postb,
    float* __restrict__ out){
  constexpr int KP_ = 136;
  __shared__ unsigned short sW[128*KP_];
  __shared__ unsigned short sX[32*KP_];
  __shared__ unsigned short sH1[32*KP_];
  __shared__ unsigned short sH2[32*KP_];
  __shared__ float sCUR[32*132];
  __shared__ float sbias[128];
  __shared__ float sg[128], sb2[128];
  __shared__ float sMean[32], sRstd[32];
  const int tid = threadIdx.x;
  const int base = blockIdx.x * 32;
  const int lane = tid & 63, wv = tid >> 6;
  const int lane15 = lane & 15, quad = lane >> 4;
  const int n0 = wv * 32;

  auto loadW = [&](const unsigned short* Wp){
    for (int i = tid; i < 2048; i += 256){
      int n = i >> 4, k8 = (i & 15) << 3;
      *(short8*)&sW[n*KP_ + k8] = *(const short8*)(Wp + (size_t)n*128 + k8);
    }
  };
  auto domfma = [&](const unsigned short* Asrc, f32x4 acc[2][2]){
    const unsigned short* aptr = Asrc + lane15*KP_ + quad*8;
    const unsigned short* bptr = sW + (size_t)(n0 + lane15)*KP_ + quad*8;
    #pragma unroll
    for (int kk=0; kk<4; kk++){
      short8 a0 = *(const short8*)(aptr + kk*32);
      short8 a1 = *(const short8*)(aptr + 16*KP_ + kk*32);
      short8 b0 = *(const short8*)(bptr + kk*32);
      short8 b1 = *(const short8*)(bptr + 16*KP_ + kk*32);
      acc[0][0] = __builtin_amdgcn_mfma_f32_16x16x32_bf16(a0,b0,acc[0][0],0,0,0);
      acc[1][0] = __builtin_amdgcn_mfma_f32_16x16x32_bf16(a1,b0,acc[1][0],0,0,0);
      acc[0][1] = __builtin_amdgcn_mfma_f32_16x16x32_bf16(a0,b1,acc[0][1],0,0,0);
      acc[1][1] = __builtin_amdgcn_mfma_f32_16x16x32_bf16(a1,b1,acc[1][1],0,0,0);
    }
  };

  loadW(WtP);
  {
    const int r = tid >> 3, part = tid & 7;
    const short8* src = (const short8*)(AOh + (size_t)(base+r)*128 + part*16);
    short8* dst = (short8*)(sX + r*KP_ + part*16);
    dst[0] = src[0]; dst[1] = src[1];
  }
  if (tid < 128){ sbias[tid] = abp[tid]; sg[tid] = png[tid]; sb2[tid] = pnb[tid]; }
  __syncthreads();
  {
    f32x4 acc[2][2];
    acc[0][0]=(f32x4)0.f; acc[0][1]=(f32x4)0.f;
    acc[1][0]=(f32x4)0.f; acc[1][1]=(f32x4)0.f;
    domfma(sX, acc);
    #pragma unroll
    for (int mt=0; mt<2; mt++)
      #pragma unroll
      for (int nt=0; nt<2; nt++){
        int col = n0 + nt*16 + lane15;
        float bsv = sbias[col];
        #pragma unroll
        for (int r4=0; r4<4; r4++){
          int row = mt*16 + quad*4 + r4;
          int rrow = base + row;
          float v = acc[mt][nt][r4] + bsv;
          if (skipmode == 1){
            int bb = rrow >> 12, l = (rrow >> 6) & 63, pp = rrow & 63;
            int pix = (((l>>3)*8 + (pp>>3)) << 6) + (l&7)*8 + (pp&7);
            v += skipf[(size_t)bb*524288 + (size_t)col*4096 + pix];
          } else {
            v += skipf[(size_t)rrow*128 + col];
          }
          sCUR[row*132 + col] = v;
        }
      }
  }
  __syncthreads();
  loadW(WtMAa);
  if (tid < 128) sbias[tid] = bma[tid];
  {
    const int r = tid >> 3, part = tid & 7;
    float v[16];
    #pragma unroll
    for (int k=0;k<16;k++) v[k] = sCUR[r*132 + part*16 + k];
    float s=0.f, s2=0.f;
    #pragma unroll
    for (int k=0;k<16;k++){ s += v[k]; s2 = fmaf(v[k],v[k],s2); }
    #pragma unroll
    for (int off=4; off>0; off>>=1){ s += __shfl_xor(s, off, 8); s2 += __shfl_xor(s2, off, 8); }
    float mean = s*(1.f/128.f);
    float rstd = rsqrtf(fmaxf(s2*(1.f/128.f) - mean*mean, 0.f) + 1e-5f);
    #pragma unroll
    for (int k=0;k<16;k++){
      int c = part*16 + k;
      v[k] = fmaf((v[k]-mean)*rstd, sg[c], sb2[c]);
    }
    store_bf16x8(sX + r*KP_ + part*16, v);
    store_bf16x8(sX + r*KP_ + part*16 + 8, v+8);
  }
  __syncthreads();
  {
    f32x4 acc[2][2];
    acc[0][0]=(f32x4)0.f; acc[0][1]=(f32x4)0.f;
    acc[1][0]=(f32x4)0.f; acc[1][1]=(f32x4)0.f;
    domfma(sX, acc);
    #pragma unroll
    for (int mt=0; mt<2; mt++)
      #pragma unroll
      for (int nt=0; nt<2; nt++){
        int col = n0 + nt*16 + lane15;
        float bsv = sbias[col];
        #pragma unroll
        for (int r4=0; r4<4; r4++){
          int row = mt*16 + quad*4 + r4;
          sH1[row*KP_ + col] = f2bf(gelu_erf(acc[mt][nt][r4] + bsv));
        }
      }
  }
  __syncthreads();
  loadW(WtMAb);
  if (tid < 128) sbias[tid] = bma[128 + tid];
  __syncthreads();
  {
    f32x4 acc[2][2];
    acc[0][0]=(f32x4)0.f; acc[0][1]=(f32x4)0.f;
    acc[1][0]=(f32x4)0.f; acc[1][1]=(f32x4)0.f;
    domfma(sX, acc);
    #pragma unroll
    for (int mt=0; mt<2; mt++)
      #pragma unroll
      for (int nt=0; nt<2; nt++){
        int col = n0 + nt*16 + lane15;
        float bsv = sbias[col];
        #pragma unroll
        for (int r4=0; r4<4; r4++){
          int row = mt*16 + quad*4 + r4;
          sH2[row*KP_ + col] = f2bf(gelu_erf(acc[mt][nt][r4] + bsv));
        }
      }
  }
  __syncthreads();
  loadW(WtMBa);
  if (tid < 128) sbias[tid] = bmb[tid];
  __syncthreads();
  f32x4 acc[2][2];
  acc[0][0]=(f32x4)0.f; acc[0][1]=(f32x4)0.f;
  acc[1][0]=(f32x4)0.f; acc[1][1]=(f32x4)0.f;
  domfma(sH1, acc);
  __syncthreads();
  loadW(WtMBb);
  __syncthreads();
  domfma(sH2, acc);
  if (out == nullptr){
    // stage 1: Q1 fp32 + fused stage-2 q projection into QPout
    #pragma unroll
    for (int mt=0; mt<2; mt++)
      #pragma unroll
      for (int nt=0; nt<2; nt++){
        int col = n0 + nt*16 + lane15;
        float bsv = sbias[col];
        #pragma unroll
        for (int r4=0; r4<4; r4++){
          int row = mt*16 + quad*4 + r4;
          float v = acc[mt][nt][r4] + bsv + sCUR[row*132 + col];
          sCUR[row*132 + col] = v;
          Q1out[(size_t)(base+row)*128 + col] = v;
        }
      }
    __syncthreads();
    {
      const int r = tid >> 3, part = tid & 7;
      float s=0.f, s2=0.f;
      #pragma unroll
      for (int k=0;k<16;k++){
        float v = sCUR[r*132 + part*16 + k];
        s += v; s2 = fmaf(v,v,s2);
      }
      #pragma unroll
      for (int off=4; off>0; off>>=1){ s += __shfl_xor(s, off, 8); s2 += __shfl_xor(s2, off, 8); }
      if (part == 0){
        float mean = s*(1.f/128.f);
        sMean[r] = mean;
        sRstd[r] = rsqrtf(fmaxf(s2*(1.f/128.f) - mean*mean, 0.f) + 1e-5f);
      }
    }
    __syncthreads();
    {
      const int r = tid >> 3, part = tid & 7;
      float mean = sMean[r], rstd = sRstd[r];
      float v[16];
      #pragma unroll
      for (int k=0;k<16;k++) v[k] = (sCUR[r*132 + part*16 + k] - mean)*rstd;
      store_bf16x8(sX + r*KP_ + part*16, v);
      store_bf16x8(sX + r*KP_ + part*16 + 8, v+8);
    }
    loadW(WtQ2);
    if (tid < 128) sbias[tid] = q2bias[tid];
    __syncthreads();
    f32x4 a2[2][2];
    a2[0][0]=(f32x4)0.f; a2[0][1]=(f32x4)0.f;
    a2[1][0]=(f32x4)0.f; a2[1][1]=(f32x4)0.f;
    domfma(sX, a2);
    #pragma unroll
    for (int mt=0; mt<2; mt++)
      #pragma unroll
      for (int nt=0; nt<2; nt++){
        int col = n0 + nt*16 + lane15;
        float bsv = sbias[col];
        #pragma unroll
        for (int r4=0; r4<4; r4++){
          int row = mt*16 + quad*4 + r4;
          sH1[row*KP_ + col] = f2bf((a2[mt][nt][r4] + bsv) * q2scale);
        }
      }
    __syncthreads();
    for (int i = tid; i < 512; i += 256){
      int row = i >> 4, seg = i & 15;
      *(short8*)(QPout + (size_t)(base+row)*128 + seg*8) = *(const short8*)&sH1[row*KP_ + seg*8];
    }
  } else {
    float res[2][2][4];
    #pragma unroll
    for (int mt=0; mt<2; mt++)
      #pragma unroll
      for (int nt=0; nt<2; nt++){
        int col = n0 + nt*16 + lane15;
        float bsv = sbias[col];
        #pragma unroll
        for (int r4=0; r4<4; r4++){
          int row = mt*16 + quad*4 + r4;
          res[mt][nt][r4] = acc[mt][nt][r4] + bsv + sCUR[row*132 + col];
        }
      }
    __syncthreads();
    #pragma unroll
    for (int mt=0; mt<2; mt++)
      #pragma unroll
      for (int nt=0; nt<2; nt++){
        int col = n0 + nt*16 + lane15;
        #pragma unroll
        for (int r4=0; r4<4; r4++){
          int row = mt*16 + quad*4 + r4;
          sCUR[row*132 + col] = res[mt][nt][r4];
        }
      }
    __syncthreads();
    {
      const int r = tid >> 3, part = tid & 7;
      float s=0.f, s2=0.f;
      #pragma unroll
      for (int k=0;k<16;k++){
        float v = sCUR[r*132 + part*16 + k];
        s += v; s2 = fmaf(v,v,s2);
      }
      #pragma unroll
      for (int off=4; off>0; off>>=1){ s += __shfl_xor(s, off, 8); s2 += __shfl_xor(s2, off, 8); }
      if (part == 0){
        float mean = s*(1.f/128.f);
        sMean[r] = mean;
        sRstd[r] = rsqrtf(fmaxf(s2*(1.f/128.f) - mean*mean, 0.f) + 1e-5f);
      }
    }
    __syncthreads();
    {
      int c = tid & 127, half = tid >> 7;
      int b = base >> 12, l = (base >> 6) & 63, p0 = base & 63;
      float go = postg[c], bo = postb[c];
      #pragma unroll
      for (int seg=0; seg<2; seg++){
        int p = p0 + half*16 + seg*8;
        int hrow = (l>>3)*8 + (p>>3);
        int w0 = (l&7)*8;
        float rr[8];
        #pragma unroll
        for (int j=0;j<8;j++){
          int row = half*16 + seg*8 + j;
          rr[j] = fmaf((sCUR[row*132 + c] - sMean[row])*sRstd[row], go, bo);
        }
        size_t obase = ((size_t)(b*128 + c))*4096 + (size_t)hrow*64 + w0;
        *(float4*)&out[obase]   = make_float4(rr[0],rr[1],rr[2],rr[3]);
        *(float4*)&out[obase+4] = make_float4(rr[4],rr[5],rr[6],rr[7]);
      }
    }
  }
}

// ---------------- MFMA attention (pair-packed V staging) --------------------
__global__ __launch_bounds__(256) void k_attn2(const unsigned short* __restrict__ QPh,
    const unsigned short* __restrict__ KPh, const unsigned short* __restrict__ VPh,
    unsigned short* __restrict__ AOh, int nrep, int nQ){
  __shared__ unsigned short Ksh[288*40];
  __shared__ unsigned short Vt[32*296];
  __shared__ unsigned short Psh[4*16*40];
  __shared__ float rs[4*16];
  int hd = blockIdx.x & 3; int bl = blockIdx.x >> 2;
  size_t kvbase = (size_t)bl*264;
  int tid = threadIdx.x;
  for (int idx = tid; idx < 1056; idx += 256){
    int row = idx >> 2, seg = idx & 3;
    *(short8*)&Ksh[row*40 + seg*8] =
      *(const short8*)(KPh + (kvbase+row)*128 + hd*32 + seg*8);
  }
  for (int idx = tid; idx < 96; idx += 256){
    int row = 264 + (idx>>2), seg = idx & 3;
    short8 z = {0,0,0,0,0,0,0,0};
    *(short8*)&Ksh[row*40 + seg*8] = z;
  }
  for (int idx = tid; idx < 528; idx += 256){   // V transpose: 132 key-pairs x 4 segs
    int kp = idx >> 2, seg = idx & 3;
    union { short8 s; unsigned short u[8]; } a, b;
    a.s = *(const short8*)(VPh + (kvbase + 2*kp)*128 + hd*32 + seg*8);
    b.s = *(const short8*)(VPh + (kvbase + 2*kp + 1)*128 + hd*32 + seg*8);
    #pragma unroll
    for (int i=0;i<8;i++)
      *(unsigned*)&Vt[(seg*8+i)*296 + 2*kp] = (unsigned)a.u[i] | ((unsigned)b.u[i] << 16);
  }
  for (int idx = tid; idx < 384; idx += 256){
    int d = idx / 12, kp = 264 + (idx % 12)*2;
    *(unsigned*)&Vt[d*296 + kp] = 0u;
  }
  __syncthreads();
  const int wv = tid >> 6, lane = tid & 63;
  const int lane15 = lane & 15, quad = lane >> 4;
  unsigned short* Pw = Psh + wv*640;
  float* rsw = rs + wv*16;
  short8 vfrag[9][2];
  #pragma unroll
  for (int kc=0; kc<9; kc++){
    vfrag[kc][0] = *(const short8*)&Vt[(lane15)*296      + kc*32 + quad*8];
    vfrag[kc][1] = *(const short8*)&Vt[(16+lane15)*296   + kc*32 + quad*8];
  }
  f32x4 macc0 = (f32x4)0.f, macc1 = (f32x4)0.f;
  for (int cam = 0; cam < nrep; cam++){
    int qrow = bl*nQ + (cam*4 + wv)*16 + lane15;
    short8 qf = *(const short8*)(QPh + (size_t)qrow*128 + hd*32 + quad*8);
    f32x4 oa0 = (f32x4)0.f, oa1 = (f32x4)0.f;
    float rsum = 0.f;
    #pragma unroll
    for (int kc=0; kc<9; kc++){
      #pragma unroll
      for (int sub=0; sub<2; sub++){
        int kt = kc*2 + sub;
        short8 kf = *(const short8*)&Ksh[(kt*16 + lane15)*40 + quad*8];
        f32x4 st = __builtin_amdgcn_mfma_f32_16x16x32_bf16(kf, qf, (f32x4)0.f, 0,0,0);
        int kbase = kt*16 + quad*4;
        float e0 = (kbase+0 < 264) ? __expf(st[0]) : 0.f;
        float e1 = (kbase+1 < 264) ? __expf(st[1]) : 0.f;
        float e2 = (kbase+2 < 264) ? __expf(st[2]) : 0.f;
        float e3 = (kbase+3 < 264) ? __expf(st[3]) : 0.f;
        rsum += (e0+e1)+(e2+e3);
        uint2 pk;
        pk.x = (unsigned)f2bf(e0) | ((unsigned)f2bf(e1) << 16);
        pk.y = (unsigned)f2bf(e2) | ((unsigned)f2bf(e3) << 16);
        *(uint2*)&Pw[lane15*40 + sub*16 + quad*4] = pk;
      }
      short8 pf = *(const short8*)&Pw[lane15*40 + quad*8];
      oa0 = __builtin_amdgcn_mfma_f32_16x16x32_bf16(pf, vfrag[kc][0], oa0, 0,0,0);
      oa1 = __builtin_amdgcn_mfma_f32_16x16x32_bf16(pf, vfrag[kc][1], oa1, 0,0,0);
    }
    rsum += __shfl_xor(rsum, 16);
    rsum += __shfl_xor(rsum, 32);
    if (lane < 16) rsw[lane] = rsum;
    f32x4 rv = *(f32x4*)&rsw[quad*4];
    #pragma unroll
    for (int r=0;r<4;r++){
      float inv = 1.f / rv[r];
      macc0[r] = fmaf(oa0[r], inv, macc0[r]);
      macc1[r] = fmaf(oa1[r], inv, macc1[r]);
    }
  }
  float sc = (nrep == 6) ? (1.f/6.f) : 1.f;
  int pixb = wv*16 + quad*4;
  #pragma unroll
  for (int r=0;r<4;r++){
    size_t rowo = ((size_t)(bl*64 + pixb + r))*128 + hd*32;
    AOh[rowo + lane15]      = f2bf(macc0[r]*sc);
    AOh[rowo + 16 + lane15] = f2bf(macc1[r]*sc);
  }
}

extern "C" void kernel_launch(void* const* d_in, const int* in_sizes, int n_in,
                              void* d_out, int out_size, void* d_ws, size_t ws_size,
                              hipStream_t stream) {
  (void)in_sizes; (void)n_in; (void)out_size; (void)ws_size;
  const float* x     = (const float*)d_in[1];
  const float* gridp = (const float*)d_in[2];
  const float* feat  = (const float*)d_in[3];
  const float* Iinv  = (const float*)d_in[4];
  const float* Einv  = (const float*)d_in[5];
  const float* gfl   = (const float*)d_in[6];
  const float* bfl   = (const float*)d_in[7];
  const float* Wfl   = (const float*)d_in[8];
  const float* gfp   = (const float*)d_in[9];
  const float* bfp   = (const float*)d_in[10];
  const float* Wfp   = (const float*)d_in[11];
  const float* Wbev  = (const float*)d_in[12];
  const float* bbev  = (const float*)d_in[13];
  const float* Wimg  = (const float*)d_in[14];
  const float* Wcam  = (const float*)d_in[15];
  const float* alng  = (const float*)d_in[16];
  const float* alnb  = (const float*)d_in[17];
  const float* aWqkv = (const float*)d_in[18];
  const float* abqkv = (const float*)d_in[19];
  const float* aWp   = (const float*)d_in[20];
  const float* abp   = (const float*)d_in[21];
  const float* png   = (const float*)d_in[22];
  const float* pnb   = (const float*)d_in[23];
  const float* Wma   = (const float*)d_in[24];
  const float* bma   = (const float*)d_in[25];
  const float* Wmb   = (const float*)d_in[26];
  const float* bmb   = (const float*)d_in[27];
  const float* postg = (const float*)d_in[28];
  const float* postb = (const float*)d_in[29];
  float* out = (float*)d_out;
  float* ws  = (float*)d_ws;
  const float QSC = 0.17677669529663687f;

  float* biasP = ws;                                   // 768 fp32 (reserve 2048)
  unsigned short* Wt   = (unsigned short*)(ws + 2048);
  unsigned short* K1h  = (unsigned short*)(ws + 149504);
  unsigned short* V1h  = K1h + 4325376;
  unsigned short* KPh  = V1h + 4325376;
  unsigned short* VPh  = KPh + 4325376;
  unsigned short* KP2h = VPh + 4325376;
  unsigned short* VP2h = KP2h + 4325376;
  unsigned short* QPh  = VP2h + 4325376;               // 49152x128
  unsigned short* Qbh  = QPh + 6291456;
  unsigned short* AOh  = Qbh + 6291456;
  float* Q1f = (float*)(AOh + 1048576);                // 8192x128 fp32

  unsigned short* WtQ1 = Wt;            unsigned short* WtK1 = Wt + 16384;
  unsigned short* WtV1 = Wt + 32768;    unsigned short* WtQ2 = Wt + 49152;
  unsigned short* WtK2 = Wt + 65536;    unsigned short* WtV2 = Wt + 81920;
  unsigned short* WtP1 = Wt + 98304;    unsigned short* WtP2 = Wt + 114688;
  unsigned short* WtMA1 = Wt + 131072;  unsigned short* WtMA2 = Wt + 163840;
  unsigned short* WtMB1a = Wt + 196608; unsigned short* WtMB1b = Wt + 212992;
  unsigned short* WtMB2a = Wt + 229376; unsigned short* WtMB2b = Wt + 245760;
  unsigned short* WtFL = Wt + 262144;   unsigned short* WtFP = Wt + 278528;

  // 1) fused prep (wprep 64 | bias-fold 6 | geom 4224 | bevq 1024)
  k_prep<<<5318, 128, 0, stream>>>(aWqkv, aWp, Wma, Wmb, Wfl, Wfp, Wt,
      Iinv, Einv, Wimg, Wcam, K1h, gridp, Wbev, bbev, x, alng, alnb,
      abqkv, biasP, Qbh);

  // 2) conv K+V + row-normalize
  k_conv<<<528, 256, 0, stream>>>(feat, gfp, bfp, WtFP, K1h,
                                  gfl, bfl, WtFL, V1h);

  // 3) Q1 + K1 + V1 + K2 + V2 projections in ONE dispatch
  {
    G5 A;
    A.g[0] = GArg{Qbh, WtQ1, biasP,      QPh,  QSC, 0};   // 384 blocks
    A.g[1] = GArg{K1h, WtK1, biasP+128,  KPh,  1.f, 1};   // 264
    A.g[2] = GArg{V1h, WtV1, biasP+256,  VPh,  1.f, 1};   // 264
    A.g[3] = GArg{K1h, WtK2, biasP+512,  KP2h, 1.f, 2};   // 264
    A.g[4] = GArg{V1h, WtV2, biasP+640,  VP2h, 1.f, 2};   // 264
    A.s[0] = 384; A.s[1] = 648; A.s[2] = 912; A.s[3] = 1176;
    k_qkv5<<<1440, 256, 0, stream>>>(A);
  }
  // 4) stage-1 attention
  k_attn2<<<512, 256, 0, stream>>>(QPh, KPh, VPh, AOh, 6, 384);
  // 5) stage-1 tail: P+x-skip+LN+MA+gelu+MB -> Q1f, then fused q2-proj -> QPh
  k_tail<<<256, 256, 0, stream>>>(AOh, x, 1, WtP1, abp, png, pnb,
      WtMA1, WtMA1+16384, bma, WtMB1a, WtMB1b, bmb, Q1f,
      WtQ2, biasP+384, QSC, QPh,
      nullptr, nullptr, nullptr);
  // 6) stage-2 attention
  k_attn2<<<512, 256, 0, stream>>>(QPh, KP2h, VP2h, AOh, 1, 64);
  // 7) stage-2 tail (+final LN) -> out
  k_tail<<<256, 256, 0, stream>>>(AOh, Q1f, 3, WtP2, abp+128, png+128, pnb+128,
      WtMA2, WtMA2+16384, bma+256, WtMB2a, WtMB2b, bmb+128, nullptr,
      nullptr, nullptr, 0.f, nullptr,
      postg, postb, out);
}